// Round 1
// baseline (170.544 us; speedup 1.0000x reference)
//
#include <hip/hip_runtime.h>
#include <hip/hip_bf16.h>

#define IN_CH   2048
#define OUT_CH  256
#define GROUPS  32
#define CPG     (OUT_CH / GROUPS)   // 8 channels per group
#define BATCH   16
#define HW      4096                // 64*64
#define EPS     1e-5f

// ---------------------------------------------------------------------------
// Kernel 1: global average pool.  One block per (b,c) row of 4096 floats.
// 256 threads x 4 float4 loads each = 16 KB coalesced per block.
// ---------------------------------------------------------------------------
__global__ __launch_bounds__(256) void pool_kernel(const float* __restrict__ x,
                                                   float* __restrict__ pooled) {
    const int row = blockIdx.x;  // b*IN_CH + c
    const float4* xr = reinterpret_cast<const float4*>(x + (size_t)row * HW);
    const int t = threadIdx.x;

    float s = 0.0f;
#pragma unroll
    for (int k = 0; k < 4; ++k) {
        float4 v = xr[t + 256 * k];
        s += (v.x + v.y) + (v.z + v.w);
    }

    // wave (64-lane) reduction
#pragma unroll
    for (int off = 32; off > 0; off >>= 1) s += __shfl_down(s, off, 64);

    __shared__ float ws[4];
    const int wid = t >> 6, lane = t & 63;
    if (lane == 0) ws[wid] = s;
    __syncthreads();
    if (t == 0) {
        float tot = (ws[0] + ws[1]) + (ws[2] + ws[3]);
        pooled[row] = tot * (1.0f / (float)HW);
    }
}

// ---------------------------------------------------------------------------
// Kernel 2: h = pooled @ W^T, then GroupNorm(32 groups of 8) + ReLU.
// One block per batch; thread o owns out-channel o.  Groups of 8 channels are
// lane-aligned (8 | 64) so mean/var reduce via __shfl_xor within the wave.
// ---------------------------------------------------------------------------
__global__ __launch_bounds__(256) void gn_kernel(const float* __restrict__ pooled,
                                                 const float* __restrict__ W,
                                                 const float* __restrict__ gamma,
                                                 const float* __restrict__ beta,
                                                 float* __restrict__ hn) {
    const int b = blockIdx.x;
    const int o = threadIdx.x;  // 0..255

    __shared__ float p[IN_CH];
    for (int c = o; c < IN_CH; c += 256) p[c] = pooled[b * IN_CH + c];
    __syncthreads();

    const float4* wr = reinterpret_cast<const float4*>(W + (size_t)o * IN_CH);
    float acc = 0.0f;
#pragma unroll 8
    for (int c4 = 0; c4 < IN_CH / 4; ++c4) {
        float4 w  = wr[c4];
        float4 pv = *reinterpret_cast<const float4*>(&p[c4 * 4]);
        acc += pv.x * w.x + pv.y * w.y + pv.z * w.z + pv.w * w.w;
    }

    // 8-lane group reduction for mean / var
    float sum = acc, sumsq = acc * acc;
#pragma unroll
    for (int m = 1; m < CPG; m <<= 1) {
        sum   += __shfl_xor(sum, m, 64);
        sumsq += __shfl_xor(sumsq, m, 64);
    }
    const float mu  = sum * (1.0f / (float)CPG);
    const float var = sumsq * (1.0f / (float)CPG) - mu * mu;
    const float r   = rsqrtf(var + EPS);

    float v = (acc - mu) * r * gamma[o] + beta[o];
    hn[b * OUT_CH + o] = fmaxf(v, 0.0f);
}

// ---------------------------------------------------------------------------
// Kernel 3: broadcast hn[b,o] to out[b,o,64,64].  float4 stores, coalesced.
// Each 1024 consecutive float4s share one hn value (wave-broadcast read).
// ---------------------------------------------------------------------------
__global__ __launch_bounds__(256) void bcast_kernel(const float* __restrict__ hn,
                                                    float4* __restrict__ out) {
    const int gid = blockIdx.x * 256 + threadIdx.x;  // float4 index
    const float v = hn[gid >> 10];                   // 1024 float4 per (b,o) plane
    out[gid] = make_float4(v, v, v, v);
}

extern "C" void kernel_launch(void* const* d_in, const int* in_sizes, int n_in,
                              void* d_out, int out_size, void* d_ws, size_t ws_size,
                              hipStream_t stream) {
    const float* x     = (const float*)d_in[0];
    const float* W     = (const float*)d_in[1];
    const float* gamma = (const float*)d_in[2];
    const float* beta  = (const float*)d_in[3];
    float* out = (float*)d_out;

    float* pooled = (float*)d_ws;                   // 16*2048 floats = 128 KiB
    float* hn     = pooled + BATCH * IN_CH;         // 16*256 floats  = 16 KiB

    pool_kernel<<<BATCH * IN_CH, 256, 0, stream>>>(x, pooled);
    gn_kernel<<<BATCH, 256, 0, stream>>>(pooled, W, gamma, beta, hn);

    const int total_f4 = BATCH * OUT_CH * (HW / 4);  // 4,194,304
    bcast_kernel<<<total_f4 / 256, 256, 0, stream>>>(hn, (float4*)out);
}

// Round 2
// 113.246 us; speedup vs baseline: 1.5060x; 1.5060x over previous
//
#include <hip/hip_runtime.h>
#include <hip/hip_bf16.h>

#define IN_CH   2048
#define OUT_CH  256
#define GROUPS  32
#define CPG     (OUT_CH / GROUPS)   // 8 channels per group
#define BATCH   16
#define HW      4096                // 64*64
#define EPS     1e-5f

// ---------------------------------------------------------------------------
// Kernel 1: global average pool.  One block per (b,c) row of 4096 floats.
// 256 threads x 4 float4 loads each = 16 KB coalesced per block.
// ---------------------------------------------------------------------------
__global__ __launch_bounds__(256) void pool_kernel(const float* __restrict__ x,
                                                   float* __restrict__ pooled) {
    const int row = blockIdx.x;  // b*IN_CH + c
    const float4* xr = reinterpret_cast<const float4*>(x + (size_t)row * HW);
    const int t = threadIdx.x;

    float s = 0.0f;
#pragma unroll
    for (int k = 0; k < 4; ++k) {
        float4 v = xr[t + 256 * k];
        s += (v.x + v.y) + (v.z + v.w);
    }

    // wave (64-lane) reduction
#pragma unroll
    for (int off = 32; off > 0; off >>= 1) s += __shfl_down(s, off, 64);

    __shared__ float ws[4];
    const int wid = t >> 6, lane = t & 63;
    if (lane == 0) ws[wid] = s;
    __syncthreads();
    if (t == 0) {
        float tot = (ws[0] + ws[1]) + (ws[2] + ws[3]);
        pooled[row] = tot * (1.0f / (float)HW);
    }
}

// ---------------------------------------------------------------------------
// Kernel 2 (fused): matmul + GroupNorm + ReLU + broadcast-write.
// One block per (batch, group): 16*32 = 512 blocks, 256 threads.
// Channel layout: ch = t>>5 (8 channels), i = t&31 (32 threads per channel).
// Threads of one channel are lanes 0-31 or 32-63 of a wave, so the 32-way dot
// reduce is __shfl_xor within a half-wave.  Group stats (8 channels spread
// over 4 waves) go through an 8-float LDS buffer.  Epilogue: each channel's
// 32 threads write its 16 KB output plane (broadcast value, float4 stores).
// ---------------------------------------------------------------------------
__global__ __launch_bounds__(256) void gn_bcast_kernel(const float* __restrict__ pooled,
                                                       const float* __restrict__ W,
                                                       const float* __restrict__ gamma,
                                                       const float* __restrict__ beta,
                                                       float4* __restrict__ out) {
    const int b = blockIdx.x >> 5;       // 0..15
    const int g = blockIdx.x & 31;       // 0..31
    const int t = threadIdx.x;
    const int ch = t >> 5;               // 0..7  (channel within group)
    const int i  = t & 31;               // 0..31 (thread within channel)
    const int o  = g * CPG + ch;         // out-channel 0..255

    // stage pooled row [2048] in LDS
    __shared__ float p[IN_CH];
    for (int c = t; c < IN_CH; c += 256) p[c] = pooled[b * IN_CH + c];
    __syncthreads();

    // dot product: thread i covers float4 indices {i, i+32, ..., i+480}
    const float4* wr = reinterpret_cast<const float4*>(W + (size_t)o * IN_CH);
    const float4* p4 = reinterpret_cast<const float4*>(p);
    float acc = 0.0f;
#pragma unroll
    for (int k = 0; k < IN_CH / 4 / 32; ++k) {   // 16 iters
        float4 w  = wr[i + 32 * k];
        float4 pv = p4[i + 32 * k];
        acc += pv.x * w.x + pv.y * w.y + pv.z * w.z + pv.w * w.w;
    }
    // 32-lane butterfly (stays within the channel's half-wave)
#pragma unroll
    for (int m = 1; m < 32; m <<= 1) acc += __shfl_xor(acc, m, 64);
    // now every lane of the channel holds h[b,o] = acc

    // group statistics across the 8 channels (cross-wave -> LDS)
    __shared__ float hsh[CPG];
    if (i == 0) hsh[ch] = acc;
    __syncthreads();
    float sum = 0.0f, sumsq = 0.0f;
#pragma unroll
    for (int c = 0; c < CPG; ++c) {
        float h = hsh[c];
        sum += h;
        sumsq += h * h;
    }
    const float mu  = sum * (1.0f / (float)CPG);
    const float var = sumsq * (1.0f / (float)CPG) - mu * mu;
    const float r   = rsqrtf(var + EPS);

    float v = fmaxf((acc - mu) * r * gamma[o] + beta[o], 0.0f);

    // broadcast-write this channel's 64x64 plane: 1024 float4, 32 per thread
    float4* outp = out + (size_t)(b * OUT_CH + o) * (HW / 4);
    const float4 v4 = make_float4(v, v, v, v);
#pragma unroll
    for (int k = 0; k < HW / 4 / 32; ++k) {      // 32 iters
        outp[i + 32 * k] = v4;
    }
}

extern "C" void kernel_launch(void* const* d_in, const int* in_sizes, int n_in,
                              void* d_out, int out_size, void* d_ws, size_t ws_size,
                              hipStream_t stream) {
    const float* x     = (const float*)d_in[0];
    const float* W     = (const float*)d_in[1];
    const float* gamma = (const float*)d_in[2];
    const float* beta  = (const float*)d_in[3];
    float* out = (float*)d_out;

    float* pooled = (float*)d_ws;                   // 16*2048 floats = 128 KiB

    pool_kernel<<<BATCH * IN_CH, 256, 0, stream>>>(x, pooled);
    gn_bcast_kernel<<<BATCH * GROUPS, 256, 0, stream>>>(pooled, W, gamma, beta,
                                                        (float4*)out);
}

// Round 4
// 100.763 us; speedup vs baseline: 1.6925x; 1.1239x over previous
//
#include <hip/hip_runtime.h>
#include <hip/hip_bf16.h>

#define IN_CH   2048
#define OUT_CH  256
#define GROUPS  32
#define CPG     (OUT_CH / GROUPS)   // 8 channels per group
#define BATCH   16
#define HW      4096                // 64*64
#define EPS     1e-5f

typedef float f32x4 __attribute__((ext_vector_type(4)));

// ---------------------------------------------------------------------------
// Kernel 1: global average pool.  One WAVE per (b,c) row of 4096 floats.
// Each lane issues 16 nontemporal float4 loads (16 KB/row, all in flight),
// accumulates in registers, 6-step shuffle butterfly, lane 0 stores.
// No LDS, no __syncthreads, no idle tail threads.
// 8192 blocks x 4 waves = 32768 rows.
// ---------------------------------------------------------------------------
__global__ __launch_bounds__(256) void pool_kernel(const float* __restrict__ x,
                                                   float* __restrict__ pooled) {
    const int w    = threadIdx.x >> 6;
    const int lane = threadIdx.x & 63;
    const int row  = blockIdx.x * 4 + w;  // b*IN_CH + c
    const f32x4* xr = reinterpret_cast<const f32x4*>(x + (size_t)row * HW);

    f32x4 a[16];
#pragma unroll
    for (int k = 0; k < 16; ++k)
        a[k] = __builtin_nontemporal_load(xr + lane + 64 * k);

    float s = 0.0f;
#pragma unroll
    for (int k = 0; k < 16; ++k)
        s += (a[k].x + a[k].y) + (a[k].z + a[k].w);

#pragma unroll
    for (int off = 32; off > 0; off >>= 1) s += __shfl_down(s, off, 64);

    if (lane == 0) pooled[row] = s * (1.0f / (float)HW);
}

// ---------------------------------------------------------------------------
// Kernel 2 (fused): matmul + GroupNorm + ReLU + broadcast-write.
// One block per (batch, group): 16*32 = 512 blocks, 256 threads.
// Channel layout: ch = t>>5 (8 channels), i = t&31 (32 threads per channel).
// ---------------------------------------------------------------------------
__global__ __launch_bounds__(256) void gn_bcast_kernel(const float* __restrict__ pooled,
                                                       const float* __restrict__ W,
                                                       const float* __restrict__ gamma,
                                                       const float* __restrict__ beta,
                                                       float4* __restrict__ out) {
    const int b = blockIdx.x >> 5;       // 0..15
    const int g = blockIdx.x & 31;       // 0..31
    const int t = threadIdx.x;
    const int ch = t >> 5;               // 0..7  (channel within group)
    const int i  = t & 31;               // 0..31 (thread within channel)
    const int o  = g * CPG + ch;         // out-channel 0..255

    // stage pooled row [2048] in LDS
    __shared__ float p[IN_CH];
    for (int c = t; c < IN_CH; c += 256) p[c] = pooled[b * IN_CH + c];
    __syncthreads();

    // dot product: thread i covers float4 indices {i, i+32, ..., i+480}
    const float4* wr = reinterpret_cast<const float4*>(W + (size_t)o * IN_CH);
    const float4* p4 = reinterpret_cast<const float4*>(p);
    float acc = 0.0f;
#pragma unroll
    for (int k = 0; k < IN_CH / 4 / 32; ++k) {   // 16 iters
        float4 w  = wr[i + 32 * k];
        float4 pv = p4[i + 32 * k];
        acc += pv.x * w.x + pv.y * w.y + pv.z * w.z + pv.w * w.w;
    }
    // 32-lane butterfly (stays within the channel's half-wave)
#pragma unroll
    for (int m = 1; m < 32; m <<= 1) acc += __shfl_xor(acc, m, 64);
    // now every lane of the channel holds h[b,o] = acc

    // group statistics across the 8 channels (cross-wave -> LDS)
    __shared__ float hsh[CPG];
    if (i == 0) hsh[ch] = acc;
    __syncthreads();
    float sum = 0.0f, sumsq = 0.0f;
#pragma unroll
    for (int c = 0; c < CPG; ++c) {
        float h = hsh[c];
        sum += h;
        sumsq += h * h;
    }
    const float mu  = sum * (1.0f / (float)CPG);
    const float var = sumsq * (1.0f / (float)CPG) - mu * mu;
    const float r   = rsqrtf(var + EPS);

    float v = fmaxf((acc - mu) * r * gamma[o] + beta[o], 0.0f);

    // broadcast-write this channel's 64x64 plane: 1024 float4, 32 per thread
    float4* outp = out + (size_t)(b * OUT_CH + o) * (HW / 4);
    const float4 v4 = make_float4(v, v, v, v);
#pragma unroll
    for (int k = 0; k < HW / 4 / 32; ++k) {      // 32 iters
        outp[i + 32 * k] = v4;
    }
}

extern "C" void kernel_launch(void* const* d_in, const int* in_sizes, int n_in,
                              void* d_out, int out_size, void* d_ws, size_t ws_size,
                              hipStream_t stream) {
    const float* x     = (const float*)d_in[0];
    const float* W     = (const float*)d_in[1];
    const float* gamma = (const float*)d_in[2];
    const float* beta  = (const float*)d_in[3];
    float* out = (float*)d_out;

    float* pooled = (float*)d_ws;                   // 16*2048 floats = 128 KiB

    pool_kernel<<<BATCH * IN_CH / 4, 256, 0, stream>>>(x, pooled);
    gn_bcast_kernel<<<BATCH * GROUPS, 256, 0, stream>>>(pooled, W, gamma, beta,
                                                        (float4*)out);
}